// Round 3
// baseline (166.594 us; speedup 1.0000x reference)
//
#include <hip/hip_runtime.h>
#include <hip/hip_bf16.h>

#define NUM_HEADS 16
#define D_K 8
#define EMBED 128
#define BATCH 8
#define SEQ 1024
#define ROWS (BATCH*SEQ)           // 8192
#define BH (BATCH*NUM_HEADS)       // 128
#define INV_SQRT_DK 0.35355339059327373f

// ---------------------------------------------------------------------------
// Kernel 1: quantum head measurement. One thread per (b,h,s) head-vector.
// z[0] = c1*...*c7 ; z[w] = c0*...*cw (w>=1), c_i = cos(x_i + theta_i).
// x fp32 [b][s][128]; writes fp32 qkv in [b*16+h][s][8] layout.
// ---------------------------------------------------------------------------
__global__ __launch_bounds__(256) void k_qlayer(const float* __restrict__ x,
                                                const float* __restrict__ theta,
                                                float* __restrict__ qkv) {
    int idx = blockIdx.x * 256 + threadIdx.x;     // (b*16+h)*1024 + s
    int b = idx >> 14;
    int h = (idx >> 10) & 15;
    int s = idx & 1023;

    const float* xp = x + ((size_t)((b << 10) + s)) * 128 + h * 8;
    float4 v0 = *(const float4*)xp;
    float4 v1 = *(const float4*)(xp + 4);

    float c0 = cosf(v0.x + theta[0]);
    float c1 = cosf(v0.y + theta[1]);
    float c2 = cosf(v0.z + theta[2]);
    float c3 = cosf(v0.w + theta[3]);
    float c4 = cosf(v1.x + theta[4]);
    float c5 = cosf(v1.y + theta[5]);
    float c6 = cosf(v1.z + theta[6]);
    float c7 = cosf(v1.w + theta[7]);

    float z1 = c0 * c1;
    float z2 = z1 * c2;
    float z3 = z2 * c3;
    float z4 = z3 * c4;
    float z5 = z4 * c5;
    float z6 = z5 * c6;
    float z7 = z6 * c7;
    float z0 = c1 * c2;
    z0 *= c3; z0 *= c4; z0 *= c5; z0 *= c6; z0 *= c7;

    float* op = qkv + (size_t)idx * 8;
    *(float4*)op       = make_float4(z0, z1, z2, z3);
    *(float4*)(op + 4) = make_float4(z4, z5, z6, z7);
}

// ---------------------------------------------------------------------------
// Kernel 2: transpose w_combine (fp32 [e][f]) -> wt (fp32 [f][e])
// ---------------------------------------------------------------------------
__global__ __launch_bounds__(256) void k_wt(const float* __restrict__ w,
                                            float* __restrict__ wt) {
    int idx = blockIdx.x * 256 + threadIdx.x;   // 16384 total
    int e = idx >> 7;
    int f = idx & 127;
    wt[f * 128 + e] = w[idx];
}

// ---------------------------------------------------------------------------
// Kernel 3: attention for one (b,h) pair, one 256-row query chunk per block.
// K/V (= same qkv tensor) staged in LDS (32 KB). No max-subtraction needed:
// |score| <= 8/sqrt(8) = 2.83, exp is safe in fp32.
// Each thread owns one query row; k_j reads are wave-uniform LDS broadcasts.
// Output layout: attn_out[b][s][h*8+i]  (row-major [8192][128], fp32).
// ---------------------------------------------------------------------------
__global__ __launch_bounds__(256) void k_attn(const float* __restrict__ qkv,
                                              float* __restrict__ attn_out) {
    __shared__ float kv[SEQ * 8];                 // 32 KB
    int bx = blockIdx.x;
    int bh = bx >> 2;                              // 0..127
    int qc = bx & 3;                               // query chunk 0..3
    int t = threadIdx.x;

    const float4* src = (const float4*)(qkv + (size_t)bh * SEQ * 8);
    float4* dst = (float4*)kv;
#pragma unroll
    for (int i = 0; i < 8; ++i)
        dst[t + 256 * i] = src[t + 256 * i];
    __syncthreads();

    int row = qc * 256 + t;
    float q[8];
#pragma unroll
    for (int i = 0; i < 8; ++i)
        q[i] = kv[row * 8 + i] * INV_SQRT_DK;      // fold 1/sqrt(d) into q

    float o0 = 0.f, o1 = 0.f, o2 = 0.f, o3 = 0.f;
    float o4 = 0.f, o5 = 0.f, o6 = 0.f, o7 = 0.f;
    float sum = 0.f;

#pragma unroll 4
    for (int j = 0; j < SEQ; ++j) {
        float4 k0 = *(const float4*)&kv[j * 8];
        float4 k1 = *(const float4*)&kv[j * 8 + 4];
        float s = q[0] * k0.x + q[1] * k0.y + q[2] * k0.z + q[3] * k0.w
                + q[4] * k1.x + q[5] * k1.y + q[6] * k1.z + q[7] * k1.w;
        float p = __expf(s);
        sum += p;
        o0 += p * k0.x; o1 += p * k0.y; o2 += p * k0.z; o3 += p * k0.w;
        o4 += p * k1.x; o5 += p * k1.y; o6 += p * k1.z; o7 += p * k1.w;
    }

    float inv = 1.0f / sum;
    int b = bh >> 4, h = bh & 15;
    float* op = attn_out + ((size_t)(b * SEQ + row)) * 128 + h * 8;
    *(float4*)op       = make_float4(o0 * inv, o1 * inv, o2 * inv, o3 * inv);
    *(float4*)(op + 4) = make_float4(o4 * inv, o5 * inv, o6 * inv, o7 * inv);
}

// ---------------------------------------------------------------------------
// Kernel 4: combine. out[r][e] = sum_f a[r][f] * w[e][f]  (= a @ w^T), FP32 out.
// Block: 8 rows x 128 cols. Thread: e = t&127, 4 rows. a[r][f] is wave-uniform
// (scalar loads); wt[f][e] reads are coalesced.
// ---------------------------------------------------------------------------
__global__ __launch_bounds__(256) void k_combine(const float* __restrict__ a,
                                                 const float* __restrict__ wt,
                                                 float* __restrict__ out) {
    int t = threadIdx.x;
    int e = t & 127;
    int half = t >> 7;                       // 0 or 1
    size_t r0 = (size_t)blockIdx.x * 8 + half * 4;
    const float* arow = a + r0 * 128;

    float acc0 = 0.f, acc1 = 0.f, acc2 = 0.f, acc3 = 0.f;
#pragma unroll 4
    for (int f = 0; f < 128; ++f) {
        float wv = wt[f * 128 + e];
        acc0 += arow[f]       * wv;
        acc1 += arow[128 + f] * wv;
        acc2 += arow[256 + f] * wv;
        acc3 += arow[384 + f] * wv;
    }
    out[(r0 + 0) * 128 + e] = acc0;
    out[(r0 + 1) * 128 + e] = acc1;
    out[(r0 + 2) * 128 + e] = acc2;
    out[(r0 + 3) * 128 + e] = acc3;
}

extern "C" void kernel_launch(void* const* d_in, const int* in_sizes, int n_in,
                              void* d_out, int out_size, void* d_ws, size_t ws_size,
                              hipStream_t stream) {
    const float* x     = (const float*)d_in[0];   // fp32 [8,1024,128]
    const float* theta = (const float*)d_in[1];   // fp32 [8]
    const float* w     = (const float*)d_in[2];   // fp32 [128,128]
    float* out = (float*)d_out;                   // fp32 [8,1024,128]

    float* qkv  = (float*)d_ws;                   // [128][1024][8]  4 MB
    float* attn = qkv + (size_t)BH * SEQ * 8;     // [8192][128]     4 MB
    float* wt   = attn + (size_t)ROWS * EMBED;    // [128][128]      64 KB

    k_qlayer<<<(BH * SEQ) / 256, 256, 0, stream>>>(x, theta, qkv);
    k_wt<<<(EMBED * EMBED) / 256, 256, 0, stream>>>(w, wt);
    k_attn<<<BH * 4, 256, 0, stream>>>(qkv, attn);
    k_combine<<<ROWS / 8, 256, 0, stream>>>(attn, wt, out);
}

// Round 5
// 165.270 us; speedup vs baseline: 1.0080x; 1.0080x over previous
//
#include <hip/hip_runtime.h>
#include <hip/hip_bf16.h>

#define NUM_HEADS 16
#define EMBED 128
#define BATCH 8
#define SEQ 1024
#define ROWS (BATCH*SEQ)           // 8192
#define QSCALE 0.5101256830f       // log2(e)/sqrt(8): p = exp(qk/sqrt8) = exp2((q*QSCALE)·k)

#if __has_builtin(__builtin_amdgcn_exp2f)
#define EXP2(x) __builtin_amdgcn_exp2f(x)
#else
#define EXP2(x) exp2f(x)
#endif

// ---------------------------------------------------------------------------
// Kernel 1: transpose w_combine (fp32 [e][f]) -> wt (fp32 [f][e])
// ---------------------------------------------------------------------------
__global__ __launch_bounds__(256) void k_wt(const float* __restrict__ w,
                                            float* __restrict__ wt) {
    int idx = blockIdx.x * 256 + threadIdx.x;   // 16384 total
    int e = idx >> 7;
    int f = idx & 127;
    wt[f * 128 + e] = w[idx];
}

// ---------------------------------------------------------------------------
// Kernel 2: fused qlayer + attention.
// Block = one (b,h) x one query-half (512 rows, 2 rows/thread). Each block
// computes z = quantum measurement for ALL 1024 rows of its (b,h) directly
// from x (cos+cumprod, ~50 inst/row, once) into 32 KB LDS, then runs the
// full-key softmax-attention loop. exp via single v_exp_f32 (exp2 with
// log2e/sqrt(8) folded into q). No max-subtraction needed: |q'.k| <= 4.09.
// Output: attn[b][s][h*8+i] fp32 (row-major [8192][128]).
// ---------------------------------------------------------------------------
__global__ __launch_bounds__(256) void k_attn(const float* __restrict__ x,
                                              const float* __restrict__ theta,
                                              float* __restrict__ attn) {
    __shared__ __align__(16) float z[SEQ * 8];     // 32 KB
    const int bid = blockIdx.x;
    const int bh = bid >> 1, qh = bid & 1;         // (b,h), query half
    const int b = bh >> 4, h = bh & 15;
    const int t = threadIdx.x;

    float th[8];
#pragma unroll
    for (int i = 0; i < 8; ++i) th[i] = theta[i];

    float q[2][8];   // this thread's 2 query rows (scaled), rows qh*512+t, +256
#pragma unroll
    for (int j = 0; j < 4; ++j) {
        int r = t + 256 * j;
        const float* xp = x + ((size_t)((b << 10) + r)) * 128 + h * 8;
        float4 a0 = *(const float4*)xp;
        float4 a1 = *(const float4*)(xp + 4);
        float c0 = cosf(a0.x + th[0]);
        float c1 = cosf(a0.y + th[1]);
        float c2 = cosf(a0.z + th[2]);
        float c3 = cosf(a0.w + th[3]);
        float c4 = cosf(a1.x + th[4]);
        float c5 = cosf(a1.y + th[5]);
        float c6 = cosf(a1.z + th[6]);
        float c7 = cosf(a1.w + th[7]);
        float z1 = c0 * c1;
        float z2 = z1 * c2;
        float z3 = z2 * c3;
        float z4 = z3 * c4;
        float z5 = z4 * c5;
        float z6 = z5 * c6;
        float z7 = z6 * c7;
        float z0 = c1 * c2;
        z0 *= c3; z0 *= c4; z0 *= c5; z0 *= c6; z0 *= c7;
        *(float4*)&z[r * 8]     = make_float4(z0, z1, z2, z3);
        *(float4*)&z[r * 8 + 4] = make_float4(z4, z5, z6, z7);
        if ((j >> 1) == qh) {                      // wave-uniform branch
            int jj = j & 1;
            q[jj][0] = z0 * QSCALE; q[jj][1] = z1 * QSCALE;
            q[jj][2] = z2 * QSCALE; q[jj][3] = z3 * QSCALE;
            q[jj][4] = z4 * QSCALE; q[jj][5] = z5 * QSCALE;
            q[jj][6] = z6 * QSCALE; q[jj][7] = z7 * QSCALE;
        }
    }
    __syncthreads();

    float o[2][8];
#pragma unroll
    for (int jj = 0; jj < 2; ++jj)
#pragma unroll
        for (int i = 0; i < 8; ++i) o[jj][i] = 0.f;
    float sm0 = 0.f, sm1 = 0.f;

#pragma unroll 4
    for (int kk = 0; kk < SEQ; ++kk) {
        float4 k0 = *(const float4*)&z[kk * 8];      // wave-uniform broadcast
        float4 k1 = *(const float4*)&z[kk * 8 + 4];
        float s0 = q[0][0]*k0.x + q[0][1]*k0.y + q[0][2]*k0.z + q[0][3]*k0.w
                 + q[0][4]*k1.x + q[0][5]*k1.y + q[0][6]*k1.z + q[0][7]*k1.w;
        float s1 = q[1][0]*k0.x + q[1][1]*k0.y + q[1][2]*k0.z + q[1][3]*k0.w
                 + q[1][4]*k1.x + q[1][5]*k1.y + q[1][6]*k1.z + q[1][7]*k1.w;
        float p0 = EXP2(s0);
        float p1 = EXP2(s1);
        sm0 += p0; sm1 += p1;
        o[0][0] += p0*k0.x; o[0][1] += p0*k0.y; o[0][2] += p0*k0.z; o[0][3] += p0*k0.w;
        o[0][4] += p0*k1.x; o[0][5] += p0*k1.y; o[0][6] += p0*k1.z; o[0][7] += p0*k1.w;
        o[1][0] += p1*k0.x; o[1][1] += p1*k0.y; o[1][2] += p1*k0.z; o[1][3] += p1*k0.w;
        o[1][4] += p1*k1.x; o[1][5] += p1*k1.y; o[1][6] += p1*k1.z; o[1][7] += p1*k1.w;
    }

    float inv0 = 1.0f / sm0;
    float inv1 = 1.0f / sm1;
    int r0 = qh * 512 + t;
    float* op = attn + ((size_t)((b << 10) + r0)) * 128 + h * 8;
    *(float4*)op       = make_float4(o[0][0]*inv0, o[0][1]*inv0, o[0][2]*inv0, o[0][3]*inv0);
    *(float4*)(op + 4) = make_float4(o[0][4]*inv0, o[0][5]*inv0, o[0][6]*inv0, o[0][7]*inv0);
    op += (size_t)256 * 128;
    *(float4*)op       = make_float4(o[1][0]*inv1, o[1][1]*inv1, o[1][2]*inv1, o[1][3]*inv1);
    *(float4*)(op + 4) = make_float4(o[1][4]*inv1, o[1][5]*inv1, o[1][6]*inv1, o[1][7]*inv1);
}

// ---------------------------------------------------------------------------
// Kernel 3: combine. out[r][e] = sum_f a[r][f] * w[e][f]  (= a @ w^T), fp32 out.
// Block: 8 rows x 128 cols. a[r][f] loads are wave-uniform (broadcast);
// wt[f][e] reads are coalesced and L2-hot.
// ---------------------------------------------------------------------------
__global__ __launch_bounds__(256) void k_combine(const float* __restrict__ a,
                                                 const float* __restrict__ wt,
                                                 float* __restrict__ out) {
    int t = threadIdx.x;
    int e = t & 127;
    int half = t >> 7;                       // 0 or 1
    size_t r0 = (size_t)blockIdx.x * 8 + half * 4;
    const float* arow = a + r0 * 128;

    float acc0 = 0.f, acc1 = 0.f, acc2 = 0.f, acc3 = 0.f;
#pragma unroll 4
    for (int f = 0; f < 128; ++f) {
        float wv = wt[f * 128 + e];
        acc0 += arow[f]       * wv;
        acc1 += arow[128 + f] * wv;
        acc2 += arow[256 + f] * wv;
        acc3 += arow[384 + f] * wv;
    }
    out[(r0 + 0) * 128 + e] = acc0;
    out[(r0 + 1) * 128 + e] = acc1;
    out[(r0 + 2) * 128 + e] = acc2;
    out[(r0 + 3) * 128 + e] = acc3;
}

extern "C" void kernel_launch(void* const* d_in, const int* in_sizes, int n_in,
                              void* d_out, int out_size, void* d_ws, size_t ws_size,
                              hipStream_t stream) {
    const float* x     = (const float*)d_in[0];   // fp32 [8,1024,128]
    const float* theta = (const float*)d_in[1];   // fp32 [8]
    const float* w     = (const float*)d_in[2];   // fp32 [128,128]
    float* out = (float*)d_out;                   // fp32 [8,1024,128]

    float* attn = (float*)d_ws;                              // [8192][128] 4 MB
    float* wt   = (float*)((char*)d_ws + (size_t)ROWS * EMBED * 4);  // [128][128] 64 KB

    k_wt<<<64, 256, 0, stream>>>(w, wt);
    k_attn<<<256, 256, 0, stream>>>(x, theta, attn);
    k_combine<<<ROWS / 8, 256, 0, stream>>>(attn, wt, out);
}

// Round 6
// 158.579 us; speedup vs baseline: 1.0505x; 1.0422x over previous
//
#include <hip/hip_runtime.h>
#include <hip/hip_bf16.h>

#define NUM_HEADS 16
#define EMBED 128
#define BATCH 8
#define SEQ 1024
#define ROWS (BATCH*SEQ)           // 8192
#define QSCALE 0.5101256830f       // log2(e)/sqrt(8): exp(qk/sqrt8) = exp2((q*QSCALE)·k)

__device__ __forceinline__ float fast_exp2(float x) {
    float r;
    asm("v_exp_f32 %0, %1" : "=v"(r) : "v"(x));   // single-inst exp2
    return r;
}

// ---------------------------------------------------------------------------
// Kernel 1: transpose w_combine (fp32 [e][f]) -> wt (fp32 [f][e])
// ---------------------------------------------------------------------------
__global__ __launch_bounds__(256) void k_wt(const float* __restrict__ w,
                                            float* __restrict__ wt) {
    int idx = blockIdx.x * 256 + threadIdx.x;   // 16384 total
    int e = idx >> 7;
    int f = idx & 127;
    wt[f * 128 + e] = w[idx];
}

// ---------------------------------------------------------------------------
// Kernel 2: fused qlayer + attention. Block = one (b,h) x one query-quarter
// (256 rows, 1 row/thread). grid 512 -> 2 blocks/CU (2 waves/SIMD) for
// latency hiding. Each block computes z for ALL 1024 rows of its (b,h)
// (cos+cumprod) into 32 KB LDS, then the full-key loop with explicit FMA
// and single-inst exp2. No max-subtraction needed: |q'.k| <= 4.09.
// ---------------------------------------------------------------------------
__global__ __launch_bounds__(256, 2) void k_attn(const float* __restrict__ x,
                                                 const float* __restrict__ theta,
                                                 float* __restrict__ attn) {
    __shared__ __align__(16) float z[SEQ * 8];     // 32 KB
    const int bid = blockIdx.x;
    const int bh = bid >> 2, qc = bid & 3;         // (b,h), query quarter
    const int b = bh >> 4, h = bh & 15;
    const int t = threadIdx.x;

    float th[8];
#pragma unroll
    for (int i = 0; i < 8; ++i) th[i] = theta[i];

    float q[8];                                    // this thread's query row
#pragma unroll
    for (int j = 0; j < 4; ++j) {
        int r = t + 256 * j;
        const float* xp = x + ((size_t)((b << 10) + r)) * 128 + h * 8;
        float4 a0 = *(const float4*)xp;
        float4 a1 = *(const float4*)(xp + 4);
        float c0 = cosf(a0.x + th[0]);
        float c1 = cosf(a0.y + th[1]);
        float c2 = cosf(a0.z + th[2]);
        float c3 = cosf(a0.w + th[3]);
        float c4 = cosf(a1.x + th[4]);
        float c5 = cosf(a1.y + th[5]);
        float c6 = cosf(a1.z + th[6]);
        float c7 = cosf(a1.w + th[7]);
        float z1 = c0 * c1;
        float z2 = z1 * c2;
        float z3 = z2 * c3;
        float z4 = z3 * c4;
        float z5 = z4 * c5;
        float z6 = z5 * c6;
        float z7 = z6 * c7;
        float z0 = c1 * c2;
        z0 *= c3; z0 *= c4; z0 *= c5; z0 *= c6; z0 *= c7;
        *(float4*)&z[r * 8]     = make_float4(z0, z1, z2, z3);
        *(float4*)&z[r * 8 + 4] = make_float4(z4, z5, z6, z7);
        if (j == qc) {                             // wave-uniform branch
            q[0] = z0 * QSCALE; q[1] = z1 * QSCALE;
            q[2] = z2 * QSCALE; q[3] = z3 * QSCALE;
            q[4] = z4 * QSCALE; q[5] = z5 * QSCALE;
            q[6] = z6 * QSCALE; q[7] = z7 * QSCALE;
        }
    }
    __syncthreads();

    float o0 = 0.f, o1 = 0.f, o2 = 0.f, o3 = 0.f;
    float o4 = 0.f, o5 = 0.f, o6 = 0.f, o7 = 0.f;
    float sm = 0.f;

#pragma unroll 4
    for (int kk = 0; kk < SEQ; ++kk) {
        float4 k0 = *(const float4*)&z[kk * 8];      // uniform broadcast
        float4 k1 = *(const float4*)&z[kk * 8 + 4];
        // 2-way split FMA chain for ILP: 7 fma + 2 mul... 9 ops
        float sa = __builtin_fmaf(q[0], k0.x,
                   __builtin_fmaf(q[1], k0.y,
                   __builtin_fmaf(q[2], k0.z, q[3] * k0.w)));
        float sb = __builtin_fmaf(q[4], k1.x,
                   __builtin_fmaf(q[5], k1.y,
                   __builtin_fmaf(q[6], k1.z, q[7] * k1.w)));
        float p = fast_exp2(sa + sb);
        sm += p;
        o0 = __builtin_fmaf(p, k0.x, o0);
        o1 = __builtin_fmaf(p, k0.y, o1);
        o2 = __builtin_fmaf(p, k0.z, o2);
        o3 = __builtin_fmaf(p, k0.w, o3);
        o4 = __builtin_fmaf(p, k1.x, o4);
        o5 = __builtin_fmaf(p, k1.y, o5);
        o6 = __builtin_fmaf(p, k1.z, o6);
        o7 = __builtin_fmaf(p, k1.w, o7);
    }

    float inv = 1.0f / sm;
    int r0 = qc * 256 + t;
    float* op = attn + ((size_t)((b << 10) + r0)) * 128 + h * 8;
    *(float4*)op       = make_float4(o0 * inv, o1 * inv, o2 * inv, o3 * inv);
    *(float4*)(op + 4) = make_float4(o4 * inv, o5 * inv, o6 * inv, o7 * inv);
}

// ---------------------------------------------------------------------------
// Kernel 3: combine. out[r][e] = sum_f a[r][f] * wt[f][e], fp32 out.
// Block: 16 rows (8 KB LDS a-tile). Thread: col e = t&127, 8 rows in
// registers. wt[f][e] coalesced from L2; a-tile via b128 LDS broadcasts.
// ---------------------------------------------------------------------------
__global__ __launch_bounds__(256, 2) void k_combine(const float* __restrict__ a,
                                                    const float* __restrict__ wt,
                                                    float* __restrict__ out) {
    __shared__ __align__(16) float at[16 * 128];   // 8 KB
    int t = threadIdx.x;
    size_t r0 = (size_t)blockIdx.x * 16;

    const float4* asrc = (const float4*)(a + r0 * 128);
    float4* adst = (float4*)at;
    adst[t]       = asrc[t];
    adst[t + 256] = asrc[t + 256];
    __syncthreads();

    int e = t & 127;
    int rg = (t >> 7) * 8;                         // row group: 0 or 8

    float acc[8];
#pragma unroll
    for (int r = 0; r < 8; ++r) acc[r] = 0.f;

#pragma unroll 8
    for (int f4 = 0; f4 < 32; ++f4) {
        int f = f4 * 4;
        float w0 = wt[(f + 0) * 128 + e];
        float w1 = wt[(f + 1) * 128 + e];
        float w2 = wt[(f + 2) * 128 + e];
        float w3 = wt[(f + 3) * 128 + e];
#pragma unroll
        for (int r = 0; r < 8; ++r) {
            float4 av = *(const float4*)&at[(rg + r) * 128 + f];  // broadcast
            acc[r] = __builtin_fmaf(av.x, w0, acc[r]);
            acc[r] = __builtin_fmaf(av.y, w1, acc[r]);
            acc[r] = __builtin_fmaf(av.z, w2, acc[r]);
            acc[r] = __builtin_fmaf(av.w, w3, acc[r]);
        }
    }

#pragma unroll
    for (int r = 0; r < 8; ++r)
        out[(r0 + rg + r) * 128 + e] = acc[r];
}

extern "C" void kernel_launch(void* const* d_in, const int* in_sizes, int n_in,
                              void* d_out, int out_size, void* d_ws, size_t ws_size,
                              hipStream_t stream) {
    const float* x     = (const float*)d_in[0];   // fp32 [8,1024,128]
    const float* theta = (const float*)d_in[1];   // fp32 [8]
    const float* w     = (const float*)d_in[2];   // fp32 [128,128]
    float* out = (float*)d_out;                   // fp32 [8,1024,128]

    float* attn = (float*)d_ws;                              // [8192][128] 4 MB
    float* wt   = (float*)((char*)d_ws + (size_t)ROWS * EMBED * 4);  // [128][128] 64 KB

    k_wt<<<64, 256, 0, stream>>>(w, wt);
    k_attn<<<512, 256, 0, stream>>>(x, theta, attn);
    k_combine<<<ROWS / 16, 256, 0, stream>>>(attn, wt, out);
}